// Round 12
// baseline (73.972 us; speedup 1.0000x reference)
//
#include <hip/hip_runtime.h>
#include <cmath>

#define BB 64
#define KK 100
#define QQ 100
#define CC 82
#define AA 118
#define KP1 101
#define AM1 117
#define ROWF (KK * KP1)      // 10100 floats per (b,a) row
#define ZB 2496              // stream blocks; each covers 3 rows of one batch
#define ZPB 39               // stream blocks per batch
#define CH4 7575             // float4 per stream block (30300 floats = 3 rows)

typedef float vf4 __attribute__((ext_vector_type(4)));

// Dispatch 1: per-batch prep. 64 blocks x 512. Writes scores/labels/boxes
// and the compacted matched list (f, coef, q) + count to workspace. The
// kernel boundary is the only cross-block fence we need (R8/R11 lesson:
// in-kernel cross-block sync on CDNA4 is either 20x-slow fences or
// residency-holding spins).
__global__ __launch_bounds__(512) void prep_kernel(
    const float* __restrict__ logits,   // B,K,C
    const float* __restrict__ boxes_in, // B,K,4
    const float* __restrict__ actions,  // B,Q,A
    const float* __restrict__ hidx,     // B,Q,K
    const float* __restrict__ oidx,     // B,Q,K
    const int*   __restrict__ tsizes,   // B,2
    float* __restrict__ out_scores,     // B,K
    float* __restrict__ out_labels,     // B,K
    float* __restrict__ out_boxes,      // B,K,4
    int*   __restrict__ wcf,            // B,Q compacted f
    float* __restrict__ wcc,            // B,Q compacted coef
    int*   __restrict__ wcq,            // B,Q compacted query
    int*   __restrict__ wsn)            // B   matched count
{
    int b = blockIdx.x;
    int tid = threadIdx.x;

    __shared__ unsigned char sh_h1[KK];   // label==1 && score>0
    __shared__ unsigned char sh_sp[KK];   // score>0
    __shared__ int   sh_h[QQ], sh_o[QQ];
    __shared__ float sh_ms[QQ];
    __shared__ float sh_c[QQ];
    __shared__ int   sh_wcnt[2];

    // ---- phase A: wave-partitioned per-k / per-q tasks ----
    if (tid < KK) {
        // softmax-lite: label (argmax over first 81), score; + boxes
        const float2* l2 = (const float2*)(logits + ((size_t)b * KK + tid) * CC);
        float m = -INFINITY, best = -INFINITY; int bi = 0;
        #pragma unroll
        for (int i = 0; i < CC / 2; ++i) {
            float2 p = l2[i];
            m = fmaxf(m, fmaxf(p.x, p.y));
            if (p.x > best) { best = p.x; bi = 2 * i; }
            if (2 * i + 1 < CC - 1 && p.y > best) { best = p.y; bi = 2 * i + 1; }
        }
        float denom = 0.f;
        #pragma unroll
        for (int i = 0; i < CC / 2; ++i) {
            float2 p = l2[i];
            denom += expf(p.x - m) + expf(p.y - m);
        }
        float score = expf(best - m) / denom;
        sh_h1[tid] = (unsigned char)((bi == 1 && score > 0.f) ? 1 : 0);
        sh_sp[tid] = (unsigned char)((score > 0.f) ? 1 : 0);
        out_scores[b * KK + tid] = score;
        out_labels[b * KK + tid] = (float)bi;

        const float4 bx = *(const float4*)(boxes_in + ((size_t)b * KK + tid) * 4);
        float ihh = (float)tsizes[b * 2 + 0];
        float iww = (float)tsizes[b * 2 + 1];
        float4 ob;
        ob.x = (bx.x - 0.5f * bx.z) * iww;
        ob.y = (bx.y - 0.5f * bx.w) * ihh;
        ob.z = (bx.x + 0.5f * bx.z) * iww;
        ob.w = (bx.y + 0.5f * bx.w) * ihh;
        *(float4*)(out_boxes + ((size_t)b * KK + tid) * 4) = ob;
    } else if (tid >= 128 && tid < 128 + QQ) {
        int q = tid - 128;  // argmax hidx (first occurrence, strict >) + ms
        const float4* rp = (const float4*)(hidx + ((size_t)b * QQ + q) * KK);
        float best = -INFINITY; int bi = 0;
        #pragma unroll
        for (int i = 0; i < KK / 4; ++i) {
            float4 r = rp[i];
            if (r.x > best) { best = r.x; bi = 4 * i; }
            if (r.y > best) { best = r.y; bi = 4 * i + 1; }
            if (r.z > best) { best = r.z; bi = 4 * i + 2; }
            if (r.w > best) { best = r.w; bi = 4 * i + 3; }
        }
        sh_h[q] = bi;
        float x = actions[((size_t)b * QQ + q) * AA + (AA - 1)];
        sh_ms[q] = 1.f - 1.f / (1.f + expf(-x));
    } else if (tid >= 256 && tid < 256 + QQ) {
        int q = tid - 256;  // argmax oidx
        const float4* rp = (const float4*)(oidx + ((size_t)b * QQ + q) * KK);
        float best = -INFINITY; int bi = 0;
        #pragma unroll
        for (int i = 0; i < KK / 4; ++i) {
            float4 r = rp[i];
            if (r.x > best) { best = r.x; bi = 4 * i; }
            if (r.y > best) { best = r.y; bi = 4 * i + 1; }
            if (r.z > best) { best = r.z; bi = 4 * i + 2; }
            if (r.w > best) { best = r.w; bi = 4 * i + 3; }
        }
        sh_o[q] = bi;
    }
    __syncthreads();

    // ---- phase B: winner-per-segment + masked coefficient ----
    if (tid < QQ) {
        int hh = sh_h[tid], oo = sh_o[tid];
        int f = hh * KP1 + oo;
        float myms = sh_ms[tid];
        bool winf = true;
        for (int q = 0; q < QQ; ++q) {
            if (sh_h[q] * KP1 + sh_o[q] == f) {
                float m2 = sh_ms[q];
                if (m2 > myms || (m2 == myms && q < tid)) { winf = false; break; }
            }
        }
        float c = myms * (winf ? 2.f : 1.f);
        if (!sh_h1[hh] || !sh_sp[oo]) c = 0.f;
        sh_c[tid] = c;
    }
    __syncthreads();

    // ---- phase C: ballot-compact matched queries (c != 0) ----
    if (tid < 128) {
        bool flag = (tid < QQ) && (sh_c[tid] != 0.f);
        unsigned long long bal = __ballot(flag);
        if ((tid & 63) == 0) sh_wcnt[tid >> 6] = __popcll(bal);
    }
    __syncthreads();
    if (tid < 128) {
        bool flag = (tid < QQ) && (sh_c[tid] != 0.f);
        unsigned long long bal = __ballot(flag);
        int base = (tid >> 6) ? sh_wcnt[0] : 0;
        if (flag) {
            int pos = base + __popcll(bal & ((1ull << (tid & 63)) - 1ull));
            wcf[b * QQ + pos] = sh_h[tid] * KP1 + sh_o[tid];
            wcc[b * QQ + pos] = sh_c[tid];
            wcq[b * QQ + pos] = tid;
        }
        if (tid == 0) wsn[b] = sh_wcnt[0] + sh_wcnt[1];
    }
}

// Dispatch 2: pure stream. Block z owns 3 contiguous (b,a) rows: streams
// 30300 float4-zeros, barrier (drains own stores), then overwrites its own
// <=3n matched cells with plain stores using the prep dispatch's list.
// No prep code in this kernel => low VGPR => fill-shaped occupancy.
__global__ __launch_bounds__(512) void stream_kernel(
    const float* __restrict__ actions, // B,Q,A
    const int*   __restrict__ wcf,
    const float* __restrict__ wcc,
    const int*   __restrict__ wcq,
    const int*   __restrict__ wsn,
    float* __restrict__ out_pair)      // B,117,100,101
{
    int z = blockIdx.x;
    int b = z / ZPB;
    int r0 = (z - b * ZPB) * 3;
    int tid = threadIdx.x;

    vf4* dst = ((vf4*)out_pair) + (size_t)z * CH4;
    const vf4 zero = {0.f, 0.f, 0.f, 0.f};
    for (int i = tid; i < CH4; i += 512) dst[i] = zero;
    __syncthreads();   // drain this block's zero stores (same block, same L2)

    int n = wsn[b];
    if (tid < 3 * n) {
        int al = tid / n;          // 0..2: local a-row
        int j  = tid - al * n;     // compacted entry index
        int fj = wcf[b * QQ + j];
        bool first = true;
        for (int i = 0; i < j; ++i)
            if (wcf[b * QQ + i] == fj) { first = false; break; }
        if (first) {
            int a = r0 + al;
            float val = 0.f;
            for (int i = j; i < n; ++i) {
                if (wcf[b * QQ + i] == fj) {
                    float x = actions[((size_t)b * QQ + wcq[b * QQ + i]) * AA + a];
                    val += wcc[b * QQ + i] / (1.f + expf(-x));
                }
            }
            ((float*)dst)[al * ROWF + fj] = val;
        }
    }
}

extern "C" void kernel_launch(void* const* d_in, const int* in_sizes, int n_in,
                              void* d_out, int out_size, void* d_ws, size_t ws_size,
                              hipStream_t stream) {
    const float* pred_logits  = (const float*)d_in[0];
    const float* pred_boxes   = (const float*)d_in[1];
    const float* pred_actions = (const float*)d_in[2];
    const float* pred_hidx    = (const float*)d_in[3];
    const float* pred_oidx    = (const float*)d_in[4];
    const int*   target_sizes = (const int*)d_in[5];

    float* out = (float*)d_out;
    float* out_scores = out;                // B*K
    float* out_labels = out + BB * KK;      // B*K
    float* out_boxes  = out + 2 * BB * KK;  // B*K*4
    float* out_pair   = out + 6 * BB * KK;  // B*117*100*101

    int*   wcf = (int*)d_ws;                 // B*Q
    float* wcc = (float*)(wcf + BB * QQ);    // B*Q
    int*   wcq = (int*)(wcc + BB * QQ);      // B*Q
    int*   wsn = wcq + BB * QQ;              // B

    prep_kernel<<<BB, 512, 0, stream>>>(
        pred_logits, pred_boxes, pred_actions, pred_hidx, pred_oidx,
        target_sizes, out_scores, out_labels, out_boxes,
        wcf, wcc, wcq, wsn);

    stream_kernel<<<ZB, 512, 0, stream>>>(
        pred_actions, wcf, wcc, wcq, wsn, out_pair);
}

// Round 13
// 55.932 us; speedup vs baseline: 1.3225x; 1.3225x over previous
//
#include <hip/hip_runtime.h>
#include <cmath>

#define BB 64
#define KK 100
#define QQ 100
#define CC 82
#define AA 118
#define KP1 101
#define AM1 117
#define ROWF (KK * KP1)          // 10100 floats per (b,a) row
#define PB 64                    // prep blocks (first in grid, overlap zeros)
#define ZB 7488                  // zero blocks: ONE a-row each (fine-grained)
#define ZCHUNK4 2525             // float4 per zero block = 1 row exactly

typedef float vf4 __attribute__((ext_vector_type(4)));

// Kernel A: blocks [0,PB): per-batch prep (scores/labels/boxes + per-query
// f/coef + compacted matched list) — launched first so their latency hides
// under the zero stream. Blocks [PB, PB+ZB): contiguous float4 zero stream,
// one 10100-float row per block (small quantum => ~1.6us dispatch granule,
// dynamic workgroup scheduling balances prep displacement and finish tail).
__global__ __launch_bounds__(512) void fused_prep_zero(
    const float* __restrict__ logits,   // B,K,C
    const float* __restrict__ boxes_in, // B,K,4
    const float* __restrict__ actions,  // B,Q,A
    const float* __restrict__ hidx,     // B,Q,K
    const float* __restrict__ oidx,     // B,Q,K
    const int*   __restrict__ tsizes,   // B,2
    float* __restrict__ out_scores,     // B,K
    float* __restrict__ out_labels,     // B,K
    float* __restrict__ out_boxes,      // B,K,4
    float* __restrict__ out_pair,       // B,117,100,101
    int*   __restrict__ wsf,            // B,Q  flat segment id
    float* __restrict__ wsc,            // B,Q  coefficient (0 if masked out)
    int*   __restrict__ wsl,            // B,Q  compacted matched-q list
    int*   __restrict__ wsn)            // B    matched count
{
    int blk = blockIdx.x;
    int tid = threadIdx.x;

    __shared__ int   sh_h[QQ], sh_o[QQ];
    __shared__ float sh_ms[QQ], sh_labf[KK];
    __shared__ int   sh_spos[KK];
    __shared__ float sh_c[QQ];
    __shared__ int   sh_wcnt[2];

    if (blk >= PB) {
        vf4* dst = ((vf4*)out_pair) + (size_t)(blk - PB) * ZCHUNK4;
        const vf4 z = {0.f, 0.f, 0.f, 0.f};
        for (int i = tid; i < ZCHUNK4; i += 512)
            dst[i] = z;
        return;
    }

    int b = blk;

    // ---- phase A: wave-partitioned per-k / per-q tasks ----
    if (tid < KK) {
        // softmax-lite: label (argmax over first 81), score; + boxes
        const float2* l2 = (const float2*)(logits + ((size_t)b * KK + tid) * CC);
        float m = -INFINITY, best = -INFINITY; int bi = 0;
        #pragma unroll
        for (int i = 0; i < CC / 2; ++i) {
            float2 p = l2[i];
            m = fmaxf(m, fmaxf(p.x, p.y));
            if (p.x > best) { best = p.x; bi = 2 * i; }
            if (2 * i + 1 < CC - 1 && p.y > best) { best = p.y; bi = 2 * i + 1; }
        }
        float denom = 0.f;
        #pragma unroll
        for (int i = 0; i < CC / 2; ++i) {
            float2 p = l2[i];
            denom += expf(p.x - m) + expf(p.y - m);
        }
        float score = expf(best - m) / denom;
        sh_labf[tid] = (float)bi;
        sh_spos[tid] = (score > 0.0f) ? 1 : 0;
        out_scores[b * KK + tid] = score;
        out_labels[b * KK + tid] = (float)bi;

        const float4 bx = *(const float4*)(boxes_in + ((size_t)b * KK + tid) * 4);
        float ihh = (float)tsizes[b * 2 + 0];
        float iww = (float)tsizes[b * 2 + 1];
        float4 ob;
        ob.x = (bx.x - 0.5f * bx.z) * iww;
        ob.y = (bx.y - 0.5f * bx.w) * ihh;
        ob.z = (bx.x + 0.5f * bx.z) * iww;
        ob.w = (bx.y + 0.5f * bx.w) * ihh;
        *(float4*)(out_boxes + ((size_t)b * KK + tid) * 4) = ob;
    } else if (tid >= 128 && tid < 128 + QQ) {
        int q = tid - 128;  // argmax hidx (first occurrence, strict >)
        const float4* rp = (const float4*)(hidx + ((size_t)b * QQ + q) * KK);
        float best = -INFINITY; int bi = 0;
        #pragma unroll
        for (int i = 0; i < KK / 4; ++i) {
            float4 r = rp[i];
            if (r.x > best) { best = r.x; bi = 4 * i; }
            if (r.y > best) { best = r.y; bi = 4 * i + 1; }
            if (r.z > best) { best = r.z; bi = 4 * i + 2; }
            if (r.w > best) { best = r.w; bi = 4 * i + 3; }
        }
        sh_h[q] = bi;
    } else if (tid >= 256 && tid < 256 + QQ) {
        int q = tid - 256;  // argmax oidx
        const float4* rp = (const float4*)(oidx + ((size_t)b * QQ + q) * KK);
        float best = -INFINITY; int bi = 0;
        #pragma unroll
        for (int i = 0; i < KK / 4; ++i) {
            float4 r = rp[i];
            if (r.x > best) { best = r.x; bi = 4 * i; }
            if (r.y > best) { best = r.y; bi = 4 * i + 1; }
            if (r.z > best) { best = r.z; bi = 4 * i + 2; }
            if (r.w > best) { best = r.w; bi = 4 * i + 3; }
        }
        sh_o[q] = bi;
    } else if (tid >= 384 && tid < 384 + QQ) {
        int q = tid - 384;  // ms = 1 - sigmoid(last action)
        float x = actions[((size_t)b * QQ + q) * AA + (AA - 1)];
        sh_ms[q] = 1.f - 1.f / (1.f + expf(-x));
    }
    __syncthreads();

    // ---- phase B: winner-per-segment + masked coefficient ----
    if (tid < QQ) {
        int hh = sh_h[tid], oo = sh_o[tid];
        int f = hh * KP1 + oo;
        float myms = sh_ms[tid];
        bool winf = true;
        for (int q = 0; q < QQ; ++q) {
            if (sh_h[q] * KP1 + sh_o[q] == f) {
                float m2 = sh_ms[q];
                if (m2 > myms || (m2 == myms && q < tid)) { winf = false; break; }
            }
        }
        float hm = (sh_labf[hh] == 1.0f && sh_spos[hh]) ? 1.f : 0.f;
        float om = sh_spos[oo] ? 1.f : 0.f;
        float c = myms * (winf ? 2.f : 1.f) * hm * om;
        sh_c[tid] = c;
        wsf[b * QQ + tid] = f;
        wsc[b * QQ + tid] = c;
    }
    __syncthreads();

    // ---- phase C: ballot-compact matched queries (c != 0) ----
    if (tid < 128) {
        bool flag = (tid < QQ) && (sh_c[tid] != 0.f);
        unsigned long long bal = __ballot(flag);
        if ((tid & 63) == 0) sh_wcnt[tid >> 6] = __popcll(bal);
    }
    __syncthreads();
    if (tid < 128) {
        bool flag = (tid < QQ) && (sh_c[tid] != 0.f);
        unsigned long long bal = __ballot(flag);
        int base = (tid >> 6) ? sh_wcnt[0] : 0;
        if (flag) {
            int pos = base + __popcll(bal & ((1ull << (tid & 63)) - 1ull));
            wsl[b * QQ + pos] = tid;
        }
        if (tid == 0) wsn[b] = sh_wcnt[0] + sh_wcnt[1];
    }
}

// Kernel B: tiny fixup. Per batch: n_matched*117 atomicAdds (expected ~150).
// Kernel boundary provides cross-XCD visibility of the zero stream.
__global__ __launch_bounds__(256) void fixup_kernel(
    const float* __restrict__ actions, // B,Q,A
    const int*   __restrict__ wsf,
    const float* __restrict__ wsc,
    const int*   __restrict__ wsl,
    const int*   __restrict__ wsn,
    float* __restrict__ out_pair)      // B,117,100,101
{
    int b = blockIdx.x;
    int tid = threadIdx.x;
    int n = wsn[b];
    int total = n * AM1;
    for (int t = tid; t < total; t += 256) {
        int j = t / AM1;
        int a = t - j * AM1;
        int q = wsl[b * QQ + j];
        float c = wsc[b * QQ + q];
        int f = wsf[b * QQ + q];
        float x = actions[((size_t)b * QQ + q) * AA + a];
        float val = c / (1.f + expf(-x));
        atomicAdd(out_pair + ((size_t)(b * AM1 + a)) * ROWF + f, val);
    }
}

extern "C" void kernel_launch(void* const* d_in, const int* in_sizes, int n_in,
                              void* d_out, int out_size, void* d_ws, size_t ws_size,
                              hipStream_t stream) {
    const float* pred_logits  = (const float*)d_in[0];
    const float* pred_boxes   = (const float*)d_in[1];
    const float* pred_actions = (const float*)d_in[2];
    const float* pred_hidx    = (const float*)d_in[3];
    const float* pred_oidx    = (const float*)d_in[4];
    const int*   target_sizes = (const int*)d_in[5];

    float* out = (float*)d_out;
    float* out_scores = out;                // B*K
    float* out_labels = out + BB * KK;      // B*K
    float* out_boxes  = out + 2 * BB * KK;  // B*K*4
    float* out_pair   = out + 6 * BB * KK;  // B*117*100*101

    int*   wsf = (int*)d_ws;                 // B*Q
    float* wsc = (float*)(wsf + BB * QQ);    // B*Q
    int*   wsl = (int*)(wsc + BB * QQ);      // B*Q
    int*   wsn = wsl + BB * QQ;              // B

    fused_prep_zero<<<PB + ZB, 512, 0, stream>>>(
        pred_logits, pred_boxes, pred_actions, pred_hidx, pred_oidx,
        target_sizes, out_scores, out_labels, out_boxes, out_pair,
        wsf, wsc, wsl, wsn);

    fixup_kernel<<<BB, 256, 0, stream>>>(pred_actions, wsf, wsc, wsl, wsn,
                                         out_pair);
}

// Round 14
// 54.957 us; speedup vs baseline: 1.3460x; 1.0178x over previous
//
#include <hip/hip_runtime.h>
#include <cmath>

#define BB 64
#define KK 100
#define QQ 100
#define CC 82
#define AA 118
#define KP1 101
#define AM1 117
#define ROWF (KK * KP1)          // 10100 floats per (b,a) row
#define NROWS (BB * AM1)         // 7488 total rows
#define PB 64                    // prep blocks (first in grid of dispatch 1)
#define Z1 6784                  // rows zeroed in dispatch 1
#define Z2 (NROWS - Z1)          // 704 rows zeroed+self-fixed in dispatch 2
#define ZCHUNK4 2525             // float4 per row

typedef float vf4 __attribute__((ext_vector_type(4)));

// Dispatch 1: blocks [0,PB) = per-batch prep (scores/labels/boxes + per-query
// f/coef + compacted matched list), hidden under the zero stream. Blocks
// [PB, PB+Z1) = one zero row each (rows [0, Z1)).
__global__ __launch_bounds__(512) void fused_prep_zero(
    const float* __restrict__ logits,   // B,K,C
    const float* __restrict__ boxes_in, // B,K,4
    const float* __restrict__ actions,  // B,Q,A
    const float* __restrict__ hidx,     // B,Q,K
    const float* __restrict__ oidx,     // B,Q,K
    const int*   __restrict__ tsizes,   // B,2
    float* __restrict__ out_scores,     // B,K
    float* __restrict__ out_labels,     // B,K
    float* __restrict__ out_boxes,      // B,K,4
    float* __restrict__ out_pair,       // B,117,100,101
    int*   __restrict__ wsf,            // B,Q  flat segment id (per query)
    float* __restrict__ wsc,            // B,Q  coefficient (0 if masked out)
    int*   __restrict__ wsl,            // B,Q  compacted matched-q list
    int*   __restrict__ wsn)            // B    matched count
{
    int blk = blockIdx.x;
    int tid = threadIdx.x;

    __shared__ int   sh_h[QQ], sh_o[QQ];
    __shared__ float sh_ms[QQ], sh_labf[KK];
    __shared__ int   sh_spos[KK];
    __shared__ float sh_c[QQ];
    __shared__ int   sh_wcnt[2];

    if (blk >= PB) {
        vf4* dst = ((vf4*)out_pair) + (size_t)(blk - PB) * ZCHUNK4;
        const vf4 z = {0.f, 0.f, 0.f, 0.f};
        for (int i = tid; i < ZCHUNK4; i += 512)
            dst[i] = z;
        return;
    }

    int b = blk;

    // ---- phase A: wave-partitioned per-k / per-q tasks ----
    if (tid < KK) {
        // softmax-lite: label (argmax over first 81), score; + boxes
        const float2* l2 = (const float2*)(logits + ((size_t)b * KK + tid) * CC);
        float m = -INFINITY, best = -INFINITY; int bi = 0;
        #pragma unroll
        for (int i = 0; i < CC / 2; ++i) {
            float2 p = l2[i];
            m = fmaxf(m, fmaxf(p.x, p.y));
            if (p.x > best) { best = p.x; bi = 2 * i; }
            if (2 * i + 1 < CC - 1 && p.y > best) { best = p.y; bi = 2 * i + 1; }
        }
        float denom = 0.f;
        #pragma unroll
        for (int i = 0; i < CC / 2; ++i) {
            float2 p = l2[i];
            denom += expf(p.x - m) + expf(p.y - m);
        }
        float score = expf(best - m) / denom;
        sh_labf[tid] = (float)bi;
        sh_spos[tid] = (score > 0.0f) ? 1 : 0;
        out_scores[b * KK + tid] = score;
        out_labels[b * KK + tid] = (float)bi;

        const float4 bx = *(const float4*)(boxes_in + ((size_t)b * KK + tid) * 4);
        float ihh = (float)tsizes[b * 2 + 0];
        float iww = (float)tsizes[b * 2 + 1];
        float4 ob;
        ob.x = (bx.x - 0.5f * bx.z) * iww;
        ob.y = (bx.y - 0.5f * bx.w) * ihh;
        ob.z = (bx.x + 0.5f * bx.z) * iww;
        ob.w = (bx.y + 0.5f * bx.w) * ihh;
        *(float4*)(out_boxes + ((size_t)b * KK + tid) * 4) = ob;
    } else if (tid >= 128 && tid < 128 + QQ) {
        int q = tid - 128;  // argmax hidx (first occurrence, strict >)
        const float4* rp = (const float4*)(hidx + ((size_t)b * QQ + q) * KK);
        float best = -INFINITY; int bi = 0;
        #pragma unroll
        for (int i = 0; i < KK / 4; ++i) {
            float4 r = rp[i];
            if (r.x > best) { best = r.x; bi = 4 * i; }
            if (r.y > best) { best = r.y; bi = 4 * i + 1; }
            if (r.z > best) { best = r.z; bi = 4 * i + 2; }
            if (r.w > best) { best = r.w; bi = 4 * i + 3; }
        }
        sh_h[q] = bi;
    } else if (tid >= 256 && tid < 256 + QQ) {
        int q = tid - 256;  // argmax oidx
        const float4* rp = (const float4*)(oidx + ((size_t)b * QQ + q) * KK);
        float best = -INFINITY; int bi = 0;
        #pragma unroll
        for (int i = 0; i < KK / 4; ++i) {
            float4 r = rp[i];
            if (r.x > best) { best = r.x; bi = 4 * i; }
            if (r.y > best) { best = r.y; bi = 4 * i + 1; }
            if (r.z > best) { best = r.z; bi = 4 * i + 2; }
            if (r.w > best) { best = r.w; bi = 4 * i + 3; }
        }
        sh_o[q] = bi;
    } else if (tid >= 384 && tid < 384 + QQ) {
        int q = tid - 384;  // ms = 1 - sigmoid(last action)
        float x = actions[((size_t)b * QQ + q) * AA + (AA - 1)];
        sh_ms[q] = 1.f - 1.f / (1.f + expf(-x));
    }
    __syncthreads();

    // ---- phase B: winner-per-segment + masked coefficient ----
    if (tid < QQ) {
        int hh = sh_h[tid], oo = sh_o[tid];
        int f = hh * KP1 + oo;
        float myms = sh_ms[tid];
        bool winf = true;
        for (int q = 0; q < QQ; ++q) {
            if (sh_h[q] * KP1 + sh_o[q] == f) {
                float m2 = sh_ms[q];
                if (m2 > myms || (m2 == myms && q < tid)) { winf = false; break; }
            }
        }
        float hm = (sh_labf[hh] == 1.0f && sh_spos[hh]) ? 1.f : 0.f;
        float om = sh_spos[oo] ? 1.f : 0.f;
        float c = myms * (winf ? 2.f : 1.f) * hm * om;
        sh_c[tid] = c;
        wsf[b * QQ + tid] = f;
        wsc[b * QQ + tid] = c;
    }
    __syncthreads();

    // ---- phase C: ballot-compact matched queries (c != 0) ----
    if (tid < 128) {
        bool flag = (tid < QQ) && (sh_c[tid] != 0.f);
        unsigned long long bal = __ballot(flag);
        if ((tid & 63) == 0) sh_wcnt[tid >> 6] = __popcll(bal);
    }
    __syncthreads();
    if (tid < 128) {
        bool flag = (tid < QQ) && (sh_c[tid] != 0.f);
        unsigned long long bal = __ballot(flag);
        int base = (tid >> 6) ? sh_wcnt[0] : 0;
        if (flag) {
            int pos = base + __popcll(bal & ((1ull << (tid & 63)) - 1ull));
            wsl[b * QQ + pos] = tid;
        }
        if (tid == 0) wsn[b] = sh_wcnt[0] + sh_wcnt[1];
    }
}

// Dispatch 2: blocks [0,Z2) zero row (Z1+bid) then self-fix its matched
// cells after a block-local barrier (no atomics/fences needed). Blocks
// [Z2, Z2+BB) write matched cells of rows < Z1 (zeroed by dispatch 1;
// kernel boundary provides visibility) via atomicAdd — this fixup work
// overlaps the Z2 blocks' streaming instead of trailing the whole stream.
__global__ __launch_bounds__(512) void tail_kernel(
    const float* __restrict__ actions, // B,Q,A
    const int*   __restrict__ wsf,
    const float* __restrict__ wsc,
    const int*   __restrict__ wsl,
    const int*   __restrict__ wsn,
    float* __restrict__ out_pair)      // B,117,100,101
{
    int bid = blockIdx.x;
    int tid = threadIdx.x;

    if (bid < Z2) {
        int r = Z1 + bid;               // global row
        int b = r / AM1;
        float* row = out_pair + (size_t)r * ROWF;
        vf4* dst = (vf4*)row;
        const vf4 z = {0.f, 0.f, 0.f, 0.f};
        for (int i = tid; i < ZCHUNK4; i += 512) dst[i] = z;
        __syncthreads();                // drain own zero stores

        int a = r - b * AM1;
        int n = wsn[b];
        if (tid < n) {
            int q = wsl[b * QQ + tid];
            int f = wsf[b * QQ + q];
            bool first = true;
            for (int i = 0; i < tid; ++i) {
                int qi = wsl[b * QQ + i];
                if (wsf[b * QQ + qi] == f) { first = false; break; }
            }
            if (first) {
                float val = 0.f;
                for (int i = tid; i < n; ++i) {
                    int qi = wsl[b * QQ + i];
                    if (wsf[b * QQ + qi] == f) {
                        float x = actions[((size_t)b * QQ + qi) * AA + a];
                        val += wsc[b * QQ + qi] / (1.f + expf(-x));
                    }
                }
                row[f] = val;
            }
        }
        return;
    }

    // writer block for batch b: cells in rows < Z1 only
    int b = bid - Z2;
    int n = wsn[b];
    int total = n * AM1;
    for (int t = tid; t < total; t += 512) {
        int j = t / AM1;
        int a = t - j * AM1;
        if (b * AM1 + a >= Z1) continue;     // handled by self-fix blocks
        int q = wsl[b * QQ + j];
        float c = wsc[b * QQ + q];
        int f = wsf[b * QQ + q];
        float x = actions[((size_t)b * QQ + q) * AA + a];
        float val = c / (1.f + expf(-x));
        atomicAdd(out_pair + ((size_t)(b * AM1 + a)) * ROWF + f, val);
    }
}

extern "C" void kernel_launch(void* const* d_in, const int* in_sizes, int n_in,
                              void* d_out, int out_size, void* d_ws, size_t ws_size,
                              hipStream_t stream) {
    const float* pred_logits  = (const float*)d_in[0];
    const float* pred_boxes   = (const float*)d_in[1];
    const float* pred_actions = (const float*)d_in[2];
    const float* pred_hidx    = (const float*)d_in[3];
    const float* pred_oidx    = (const float*)d_in[4];
    const int*   target_sizes = (const int*)d_in[5];

    float* out = (float*)d_out;
    float* out_scores = out;                // B*K
    float* out_labels = out + BB * KK;      // B*K
    float* out_boxes  = out + 2 * BB * KK;  // B*K*4
    float* out_pair   = out + 6 * BB * KK;  // B*117*100*101

    int*   wsf = (int*)d_ws;                 // B*Q
    float* wsc = (float*)(wsf + BB * QQ);    // B*Q
    int*   wsl = (int*)(wsc + BB * QQ);      // B*Q
    int*   wsn = wsl + BB * QQ;              // B

    fused_prep_zero<<<PB + Z1, 512, 0, stream>>>(
        pred_logits, pred_boxes, pred_actions, pred_hidx, pred_oidx,
        target_sizes, out_scores, out_labels, out_boxes, out_pair,
        wsf, wsc, wsl, wsn);

    tail_kernel<<<Z2 + BB, 512, 0, stream>>>(
        pred_actions, wsf, wsc, wsl, wsn, out_pair);
}

// Round 15
// 51.420 us; speedup vs baseline: 1.4386x; 1.0688x over previous
//
#include <hip/hip_runtime.h>
#include <cmath>

#define BB 64
#define KK 100
#define QQ 100
#define CC 82
#define AA 118
#define KP1 101
#define AM1 117
#define ROWF (KK * KP1)          // 10100 floats per (b,a) row
#define NROWS (BB * AM1)         // 7488 rows
#define PB 64                    // prep blocks (first in grid)
#define ZCHUNK4 2525             // float4 per row
#define ECAP 16                  // max entries read opportunistically

typedef float vf4 __attribute__((ext_vector_type(4)));
typedef unsigned long long u64;

#define MAGICC 0x5EA1C0DEULL     // count-word magic (high 32 bits)
#define MAGICE 0x5AULL           // entry magic (high 8 bits)

// Dispatch 1.
// blocks [0,PB): per-batch prep -> small outputs + plain workspace arrays
//   (for cleanup) + magic-tagged atomic words (for opportunistic readers).
// blocks [PB, PB+NROWS): zero one row; read the batch's published list with
//   <=17 parallel device-scope atomic loads issued BEFORE the zero loop
//   (latency hidden under stores); if valid -> plain-store own row's value
//   cells after the block barrier and flag=0; else flag=1 for cleanup.
__global__ __launch_bounds__(512) void fused_prep_zero(
    const float* __restrict__ logits,   // B,K,C
    const float* __restrict__ boxes_in, // B,K,4
    const float* __restrict__ actions,  // B,Q,A
    const float* __restrict__ hidx,     // B,Q,K
    const float* __restrict__ oidx,     // B,Q,K
    const int*   __restrict__ tsizes,   // B,2
    float* __restrict__ out_scores,     // B,K
    float* __restrict__ out_labels,     // B,K
    float* __restrict__ out_boxes,      // B,K,4
    float* __restrict__ out_pair,       // B,117,100,101
    u64*   __restrict__ pub,            // B*(QQ+1) atomic publish words
    int*   __restrict__ wsf,            // B,Q per-query flat segment id
    float* __restrict__ wsc,            // B,Q per-query coefficient
    int*   __restrict__ wsl,            // B,Q compacted matched-q list
    int*   __restrict__ wsn,            // B   matched count
    int*   __restrict__ flags)          // NROWS 1=needs cleanup
{
    int blk = blockIdx.x;
    int tid = threadIdx.x;

    if (blk >= PB) {
        // ---------------- zero block: one row ----------------
        int r = blk - PB;
        int b = r / AM1;
        int a = r - b * AM1;
        u64* pubb = pub + (size_t)b * (QQ + 1);

        __shared__ u64 sh_cw, sh_e[ECAP];
        __shared__ int sh_bad;
        __shared__ int cp_f[ECAP], cp_q[ECAP];
        __shared__ float cp_c[ECAP];

        u64 cw = 0, ent = 0;
        if (tid == 0) { cw = atomicAdd(pubb, 0ULL); sh_bad = 0; }
        else if (tid <= ECAP) ent = atomicAdd(pubb + tid, 0ULL);

        vf4* dst = ((vf4*)out_pair) + (size_t)r * ZCHUNK4;
        const vf4 z = {0.f, 0.f, 0.f, 0.f};
        for (int i = tid; i < ZCHUNK4; i += 512) dst[i] = z;

        if (tid == 0) sh_cw = cw;
        else if (tid <= ECAP) sh_e[tid - 1] = ent;
        __syncthreads();   // zero stores drained; LDS stashes visible

        u64 c0 = sh_cw;
        bool ready = ((c0 >> 32) == MAGICC);
        int n = ready ? (int)(c0 & 0xFFFFFFFFULL) : 0;
        if (n > ECAP) ready = false;
        if (ready && tid < n && ((sh_e[tid] >> 56) != MAGICE)) sh_bad = 1;
        __syncthreads();

        bool fix = ready && !sh_bad;
        if (tid == 0) flags[r] = fix ? 0 : 1;
        if (!fix || n == 0) return;

        if (tid < n) {
            u64 e = sh_e[tid];
            cp_q[tid] = (int)(e & 0x3FF);
            cp_f[tid] = (int)((e >> 10) & 0x3FFF);
            cp_c[tid] = __uint_as_float((unsigned)(e >> 24));
        }
        __syncthreads();

        if (tid < n) {
            int j = tid, fj = cp_f[j];
            bool first = true;
            for (int i = 0; i < j; ++i)
                if (cp_f[i] == fj) { first = false; break; }
            if (first) {
                float val = 0.f;
                for (int i = j; i < n; ++i) {
                    if (cp_f[i] == fj) {
                        float x = actions[((size_t)b * QQ + cp_q[i]) * AA + a];
                        val += cp_c[i] / (1.f + expf(-x));
                    }
                }
                ((float*)dst)[fj] = val;
            }
        }
        return;
    }

    // ---------------- prep block: batch b ----------------
    int b = blk;
    __shared__ int   sh_h[QQ], sh_o[QQ];
    __shared__ float sh_ms[QQ], sh_labf[KK];
    __shared__ int   sh_spos[KK];
    __shared__ float sh_c[QQ];
    __shared__ int   sh_wcnt[2];
    __shared__ int   cpf[QQ], cpq[QQ];
    __shared__ float cpc[QQ];

    if (tid < KK) {
        const float2* l2 = (const float2*)(logits + ((size_t)b * KK + tid) * CC);
        float m = -INFINITY, best = -INFINITY; int bi = 0;
        #pragma unroll
        for (int i = 0; i < CC / 2; ++i) {
            float2 p = l2[i];
            m = fmaxf(m, fmaxf(p.x, p.y));
            if (p.x > best) { best = p.x; bi = 2 * i; }
            if (2 * i + 1 < CC - 1 && p.y > best) { best = p.y; bi = 2 * i + 1; }
        }
        float denom = 0.f;
        #pragma unroll
        for (int i = 0; i < CC / 2; ++i) {
            float2 p = l2[i];
            denom += expf(p.x - m) + expf(p.y - m);
        }
        float score = expf(best - m) / denom;
        sh_labf[tid] = (float)bi;
        sh_spos[tid] = (score > 0.0f) ? 1 : 0;
        out_scores[b * KK + tid] = score;
        out_labels[b * KK + tid] = (float)bi;

        const float4 bx = *(const float4*)(boxes_in + ((size_t)b * KK + tid) * 4);
        float ihh = (float)tsizes[b * 2 + 0];
        float iww = (float)tsizes[b * 2 + 1];
        float4 ob;
        ob.x = (bx.x - 0.5f * bx.z) * iww;
        ob.y = (bx.y - 0.5f * bx.w) * ihh;
        ob.z = (bx.x + 0.5f * bx.z) * iww;
        ob.w = (bx.y + 0.5f * bx.w) * ihh;
        *(float4*)(out_boxes + ((size_t)b * KK + tid) * 4) = ob;
    } else if (tid >= 128 && tid < 128 + QQ) {
        int q = tid - 128;  // argmax hidx (first occurrence, strict >)
        const float4* rp = (const float4*)(hidx + ((size_t)b * QQ + q) * KK);
        float best = -INFINITY; int bi = 0;
        #pragma unroll
        for (int i = 0; i < KK / 4; ++i) {
            float4 rr = rp[i];
            if (rr.x > best) { best = rr.x; bi = 4 * i; }
            if (rr.y > best) { best = rr.y; bi = 4 * i + 1; }
            if (rr.z > best) { best = rr.z; bi = 4 * i + 2; }
            if (rr.w > best) { best = rr.w; bi = 4 * i + 3; }
        }
        sh_h[q] = bi;
    } else if (tid >= 256 && tid < 256 + QQ) {
        int q = tid - 256;  // argmax oidx
        const float4* rp = (const float4*)(oidx + ((size_t)b * QQ + q) * KK);
        float best = -INFINITY; int bi = 0;
        #pragma unroll
        for (int i = 0; i < KK / 4; ++i) {
            float4 rr = rp[i];
            if (rr.x > best) { best = rr.x; bi = 4 * i; }
            if (rr.y > best) { best = rr.y; bi = 4 * i + 1; }
            if (rr.z > best) { best = rr.z; bi = 4 * i + 2; }
            if (rr.w > best) { best = rr.w; bi = 4 * i + 3; }
        }
        sh_o[q] = bi;
    } else if (tid >= 384 && tid < 384 + QQ) {
        int q = tid - 384;  // ms = 1 - sigmoid(last action)
        float x = actions[((size_t)b * QQ + q) * AA + (AA - 1)];
        sh_ms[q] = 1.f - 1.f / (1.f + expf(-x));
    }
    __syncthreads();

    if (tid < QQ) {
        int hh = sh_h[tid], oo = sh_o[tid];
        int f = hh * KP1 + oo;
        float myms = sh_ms[tid];
        bool winf = true;
        for (int q = 0; q < QQ; ++q) {
            if (sh_h[q] * KP1 + sh_o[q] == f) {
                float m2 = sh_ms[q];
                if (m2 > myms || (m2 == myms && q < tid)) { winf = false; break; }
            }
        }
        float hm = (sh_labf[hh] == 1.0f && sh_spos[hh]) ? 1.f : 0.f;
        float om = sh_spos[oo] ? 1.f : 0.f;
        float c = myms * (winf ? 2.f : 1.f) * hm * om;
        sh_c[tid] = c;
        wsf[b * QQ + tid] = f;
        wsc[b * QQ + tid] = c;
    }
    __syncthreads();

    if (tid < 128) {
        bool flag = (tid < QQ) && (sh_c[tid] != 0.f);
        unsigned long long bal = __ballot(flag);
        if ((tid & 63) == 0) sh_wcnt[tid >> 6] = __popcll(bal);
    }
    __syncthreads();
    if (tid < 128) {
        bool flag = (tid < QQ) && (sh_c[tid] != 0.f);
        unsigned long long bal = __ballot(flag);
        int base = (tid >> 6) ? sh_wcnt[0] : 0;
        if (flag) {
            int pos = base + __popcll(bal & ((1ull << (tid & 63)) - 1ull));
            wsl[b * QQ + pos] = tid;
            cpf[pos] = sh_h[tid] * KP1 + sh_o[tid];
            cpq[pos] = tid;
            cpc[pos] = sh_c[tid];
        }
        if (tid == 0) wsn[b] = sh_wcnt[0] + sh_wcnt[1];
    }
    __syncthreads();

    // publish magic-tagged entries + count (per-word self-validating; no
    // ordering requirements; poison 0xAA.. fails both magic checks).
    int n = sh_wcnt[0] + sh_wcnt[1];
    u64* pubb = pub + (size_t)b * (QQ + 1);
    if (tid < n) {
        u64 e = (MAGICE << 56)
              | ((u64)__float_as_uint(cpc[tid]) << 24)
              | ((u64)cpf[tid] << 10)
              | (u64)cpq[tid];
        atomicExch(pubb + 1 + tid, e);
    }
    if (tid == 0) atomicExch(pubb, (MAGICC << 32) | (u64)n);
}

// Dispatch 2: cleanup. 64 blocks; block b writes value cells only for its
// flagged rows (zeroed in dispatch 1; boundary gives visibility; flagged
// rows were NOT touched by self-fix -> plain stores, no contention).
// Summation order identical to the self-fix path -> bit-identical output.
__global__ __launch_bounds__(512) void cleanup_kernel(
    const float* __restrict__ actions, // B,Q,A
    const int*   __restrict__ wsf,
    const float* __restrict__ wsc,
    const int*   __restrict__ wsl,
    const int*   __restrict__ wsn,
    const int*   __restrict__ flags,
    float* __restrict__ out_pair)      // B,117,100,101
{
    int b = blockIdx.x;
    int tid = threadIdx.x;
    int n = wsn[b];
    int total = AM1 * n;
    for (int t = tid; t < total; t += 512) {
        int a = t / n;
        int j = t - a * n;
        int r = b * AM1 + a;
        if (!flags[r]) continue;
        int qj = wsl[b * QQ + j];
        int fj = wsf[b * QQ + qj];
        bool first = true;
        for (int i = 0; i < j; ++i) {
            int qi = wsl[b * QQ + i];
            if (wsf[b * QQ + qi] == fj) { first = false; break; }
        }
        if (first) {
            float val = 0.f;
            for (int i = j; i < n; ++i) {
                int qi = wsl[b * QQ + i];
                if (wsf[b * QQ + qi] == fj) {
                    float x = actions[((size_t)b * QQ + qi) * AA + a];
                    val += wsc[b * QQ + qi] / (1.f + expf(-x));
                }
            }
            out_pair[(size_t)r * ROWF + fj] = val;
        }
    }
}

extern "C" void kernel_launch(void* const* d_in, const int* in_sizes, int n_in,
                              void* d_out, int out_size, void* d_ws, size_t ws_size,
                              hipStream_t stream) {
    const float* pred_logits  = (const float*)d_in[0];
    const float* pred_boxes   = (const float*)d_in[1];
    const float* pred_actions = (const float*)d_in[2];
    const float* pred_hidx    = (const float*)d_in[3];
    const float* pred_oidx    = (const float*)d_in[4];
    const int*   target_sizes = (const int*)d_in[5];

    float* out = (float*)d_out;
    float* out_scores = out;                // B*K
    float* out_labels = out + BB * KK;      // B*K
    float* out_boxes  = out + 2 * BB * KK;  // B*K*4
    float* out_pair   = out + 6 * BB * KK;  // B*117*100*101

    u64*   pub = (u64*)d_ws;                     // B*(QQ+1) u64 (8B aligned)
    int*   wsf = (int*)(pub + BB * (QQ + 1));    // B*Q
    float* wsc = (float*)(wsf + BB * QQ);        // B*Q
    int*   wsl = (int*)(wsc + BB * QQ);          // B*Q
    int*   wsn = wsl + BB * QQ;                  // B
    int*   flags = wsn + BB;                     // NROWS

    fused_prep_zero<<<PB + NROWS, 512, 0, stream>>>(
        pred_logits, pred_boxes, pred_actions, pred_hidx, pred_oidx,
        target_sizes, out_scores, out_labels, out_boxes, out_pair,
        pub, wsf, wsc, wsl, wsn, flags);

    cleanup_kernel<<<BB, 512, 0, stream>>>(
        pred_actions, wsf, wsc, wsl, wsn, flags, out_pair);
}